// Round 14
// baseline (307.456 us; speedup 1.0000x reference)
//
#include <hip/hip_runtime.h>

// ---------------------------------------------------------------------------
// GCN forward, all-fp16 MFMA edition.
// Round 14 (consolidation): merge count_deg+prep+wf into one range-partitioned
//   build kernel (-2 launches); nontemporal col loads + h/a1 stores in the
//   aggregates (preserve L2 for the tmp gather). Aggregates are at the
//   measured ~3.6-3.9 TB/s random-row-gather fabric ceiling with compulsory
//   bytes (r6: chunking raises bytes; r4: ILP-neutral); CSR is atomic/scatter
//   bound; GEMMs small-N latency-bound. Everything else verbatim round 13.
// ---------------------------------------------------------------------------

typedef __attribute__((ext_vector_type(8))) _Float16 half8;
typedef __attribute__((ext_vector_type(4))) _Float16 half4v;
typedef __attribute__((ext_vector_type(4))) float f32x4;

__device__ __forceinline__ void fma4h(float4& acc, float s, const half4v& v) {
  acc.x += s * (float)v.x;
  acc.y += s * (float)v.y;
  acc.z += s * (float)v.z;
  acc.w += s * (float)v.w;
}

// ---------------------------------------------------------------------------
// Merged build kernel: [0,E) degree count + rank; [E,E+nx4) x cast;
// then W2/W3 transpose-cast; then Wf = (encW@W1)^T fp16 + cvec = enc_b@W1.
// All ranges independent.
// ---------------------------------------------------------------------------
__global__ void build_kernel(const int* __restrict__ dst, int* __restrict__ deg,
                             int* __restrict__ rank, int E,
                             const float* __restrict__ x, _Float16* __restrict__ xh, int nx4,
                             const float* __restrict__ W2, const float* __restrict__ W3,
                             _Float16* __restrict__ Wt2, _Float16* __restrict__ Wt3,
                             const float* __restrict__ encW, const float* __restrict__ enc_b,
                             const float* __restrict__ W1, _Float16* __restrict__ Wtf,
                             float* __restrict__ cvec) {
  int t = blockIdx.x * blockDim.x + threadIdx.x;
  if (t < E) {                              // degree + rank (single atomic pass)
    rank[t] = atomicAdd(&deg[dst[t]], 1);
    return;
  }
  int u = t - E;
  if (u < nx4) {                            // x f32 -> fp16 (float4-wide)
    float4 v = ((const float4*)x)[u];
    half4v h;
    h.x = (_Float16)v.x; h.y = (_Float16)v.y; h.z = (_Float16)v.z; h.w = (_Float16)v.w;
    ((half4v*)xh)[u] = h;
    return;
  }
  u -= nx4;
  if (u < 2 * 256 * 256) {                  // W2/W3 [256][256] -> Wt [256][256]^T
    int seg = u >> 16;
    int rem = u & 65535;
    int k = rem >> 8, n = rem & 255;
    const float* W = (seg == 0) ? W2 : W3;
    _Float16* Wt = (seg == 0) ? Wt2 : Wt3;
    Wt[(size_t)n * 256 + k] = (_Float16)W[rem];
    return;
  }
  u -= 2 * 256 * 256;
  if (u >= 129 * 256) return;               // fused weight: Wtf + cvec
  int k = u >> 8;                           // 0..127 = Wf rows; 128 = cvec
  int nn = u & 255;
  float s = 0.f;
  if (k < 128) {
    for (int m = 0; m < 256; ++m)
      s += encW[k * 256 + m] * W1[m * 256 + nn];
    Wtf[(size_t)nn * 128 + k] = (_Float16)s;
  } else {
    for (int m = 0; m < 256; ++m)
      s += enc_b[m] * W1[m * 256 + nn];
    cvec[nn] = s;
  }
}

// scan phase 1 + dinv fused (cnt[i] = deg[i]+1 folds the self-loop).
__global__ __launch_bounds__(1024) void scan1_kernel(const int* __restrict__ deg,
                                                     float* __restrict__ dinv,
                                                     int* __restrict__ row_tmp,
                                                     int* __restrict__ bsum, int n) {
  __shared__ int wsum[16];
  int tid = threadIdx.x, lane = tid & 63, wid = tid >> 6;
  int i = blockIdx.x * 1024 + tid;
  int d = (i < n) ? deg[i] + 1 : 0;
  if (i < n) dinv[i] = rsqrtf((float)d);
  int v = d;
  int s = v;
#pragma unroll
  for (int off = 1; off < 64; off <<= 1) {
    int t = __shfl_up(s, off, 64);
    if (lane >= off) s += t;
  }
  if (lane == 63) wsum[wid] = s;
  __syncthreads();
  int wadd = 0;
#pragma unroll
  for (int k = 0; k < 16; ++k) wadd += (k < wid) ? wsum[k] : 0;
  int incl = s + wadd;
  if (i < n) row_tmp[i] = incl - v;          // block-local exclusive
  if (tid == 1023) bsum[blockIdx.x] = incl;  // block total
}
__global__ __launch_bounds__(64) void scan2_kernel(const int* __restrict__ bsum,
                                                   int* __restrict__ boff,
                                                   int* __restrict__ row_ptr,
                                                   int n, int nb) {
  int lane = threadIdx.x;
  int v = (lane < nb) ? bsum[lane] : 0;
  int s = v;
#pragma unroll
  for (int off = 1; off < 64; off <<= 1) {
    int t = __shfl_up(s, off, 64);
    if (lane >= off) s += t;
  }
  if (lane < nb) boff[lane] = s - v;
  if (lane == nb - 1) row_ptr[n] = s;
}
__global__ __launch_bounds__(1024) void scan3_kernel(const int* __restrict__ row_tmp,
                                                     const int* __restrict__ boff,
                                                     int* __restrict__ row_ptr, int n) {
  int i = blockIdx.x * 1024 + threadIdx.x;
  if (i >= n) return;
  row_ptr[i] = row_tmp[i] + boff[blockIdx.x];
}

// fill edges + self-loops, NO atomics: pos = row_ptr[dst]+1+rank (slot 0 = self).
__global__ void fill_csr_kernel(const int* __restrict__ src, const int* __restrict__ dst,
                                const int* __restrict__ row_ptr, const int* __restrict__ rank,
                                int* __restrict__ col, int E, int n) {
  int t = blockIdx.x * blockDim.x + threadIdx.x;
  if (t < E) {
    int d = dst[t];
    col[row_ptr[d] + 1 + rank[t]] = src[t];
  } else if (t < E + n) {
    int i = t - E;
    col[row_ptr[i]] = i;
  }
}

// ---------------------------------------------------------------------------
// Aggregate x: a1 = A_hat @ xh ([N,128]), rs = A_hat row sums.
// 32-lane group per node, half4/lane, 8 nodes/block.
// ---------------------------------------------------------------------------
__global__ __launch_bounds__(256) void aggregate_x_kernel(
    const _Float16* __restrict__ xh, const int* __restrict__ row_ptr,
    const int* __restrict__ col, const float* __restrict__ dinv,
    _Float16* __restrict__ a1, float* __restrict__ rs, int n) {
  int grp = threadIdx.x >> 5;
  int gl = threadIdx.x & 31;
  int node = blockIdx.x * 8 + grp;
  if (node >= n) return;
  const half4v* x4 = (const half4v*)xh;
  float dn = dinv[node];
  float4 a0 = make_float4(0.f, 0.f, 0.f, 0.f);
  float4 b0 = make_float4(0.f, 0.f, 0.f, 0.f);
  float4 c0 = make_float4(0.f, 0.f, 0.f, 0.f);
  float4 e0 = make_float4(0.f, 0.f, 0.f, 0.f);
  float dsum = 0.f;
  int p = row_ptr[node], end = row_ptr[node + 1];

  for (; p + 8 <= end; p += 8) {
    int j0 = __builtin_nontemporal_load(&col[p + 0]);
    int j1 = __builtin_nontemporal_load(&col[p + 1]);
    int j2 = __builtin_nontemporal_load(&col[p + 2]);
    int j3 = __builtin_nontemporal_load(&col[p + 3]);
    int j4 = __builtin_nontemporal_load(&col[p + 4]);
    int j5 = __builtin_nontemporal_load(&col[p + 5]);
    int j6 = __builtin_nontemporal_load(&col[p + 6]);
    int j7 = __builtin_nontemporal_load(&col[p + 7]);
    float d0 = dinv[j0], d1 = dinv[j1], d2 = dinv[j2], d3 = dinv[j3];
    float d4 = dinv[j4], d5 = dinv[j5], d6 = dinv[j6], d7 = dinv[j7];
    half4v v0 = x4[(size_t)j0 * 32 + gl];
    half4v v1 = x4[(size_t)j1 * 32 + gl];
    half4v v2 = x4[(size_t)j2 * 32 + gl];
    half4v v3 = x4[(size_t)j3 * 32 + gl];
    half4v v4 = x4[(size_t)j4 * 32 + gl];
    half4v v5 = x4[(size_t)j5 * 32 + gl];
    half4v v6 = x4[(size_t)j6 * 32 + gl];
    half4v v7 = x4[(size_t)j7 * 32 + gl];
    fma4h(a0, d0, v0); fma4h(b0, d1, v1); fma4h(c0, d2, v2); fma4h(e0, d3, v3);
    fma4h(a0, d4, v4); fma4h(b0, d5, v5); fma4h(c0, d6, v6); fma4h(e0, d7, v7);
    dsum += ((d0 + d1) + (d2 + d3)) + ((d4 + d5) + (d6 + d7));
  }
  for (; p < end; ++p) {
    int j = __builtin_nontemporal_load(&col[p]);
    float d = dinv[j];
    half4v v = x4[(size_t)j * 32 + gl];
    fma4h(a0, d, v);
    dsum += d;
  }
  float4 acc;
  acc.x = (a0.x + b0.x + c0.x + e0.x) * dn;
  acc.y = (a0.y + b0.y + c0.y + e0.y) * dn;
  acc.z = (a0.z + b0.z + c0.z + e0.z) * dn;
  acc.w = (a0.w + b0.w + c0.w + e0.w) * dn;
  half4v hv;
  hv.x = (_Float16)acc.x; hv.y = (_Float16)acc.y;
  hv.z = (_Float16)acc.z; hv.w = (_Float16)acc.w;
  __builtin_nontemporal_store(hv, &((half4v*)a1)[(size_t)node * 32 + gl]);
  if (gl == 0) rs[node] = dsum * dn;
}

// ---------------------------------------------------------------------------
// fp16 MFMA GEMM (round-9 proven form). NCHUNK = K/64 (2 or 4).
// OUTMODE 0: f16 out. OUTMODE 2: +rs*cvec+bias, relu, f16 out.
// ---------------------------------------------------------------------------
template<int NCHUNK, int OUTMODE>
__global__ __launch_bounds__(256) void mfma_gemm_kernel(
    const _Float16* __restrict__ A, const _Float16* __restrict__ Bt,
    const float* __restrict__ bias, const float* __restrict__ rs,
    const float* __restrict__ cvec, _Float16* __restrict__ outp, int M) {
  constexpr int K = NCHUNK * 64;
  __shared__ __align__(16) _Float16 As[2 * 128 * 64];   // 32 KB
  __shared__ __align__(16) _Float16 Bs[2 * 128 * 64];   // 32 KB
  int row0 = (blockIdx.x >> 1) * 128;
  int col0 = (blockIdx.x & 1) * 128;
  int tid = threadIdx.x;
  int w = tid >> 6, l = tid & 63;
  int wm = w >> 1, wn = w & 1;

  f32x4 acc[4][4] = {};

  int srow = l >> 3;
  int sslot = (l & 7) ^ srow;
  int fr_a = wm * 64 + (l & 15);
  int fr_b = wn * 64 + (l & 15);
  int fgrp = l >> 4;

#pragma unroll
  for (int ph = 0; ph < NCHUNK / 2; ++ph) {
#pragma unroll
    for (int c = 0; c < 2; ++c) {
      int kb = (ph * 2 + c) * 64;
#pragma unroll
      for (int q = 0; q < 4; ++q) {
        int r = w * 32 + q * 8 + srow;
        int ga_row = row0 + r; if (ga_row >= M) ga_row = M - 1;
        const _Float16* gA = A + (size_t)ga_row * K + kb + sslot * 8;
        __builtin_amdgcn_global_load_lds(
            (const __attribute__((address_space(1))) void*)gA,
            (__attribute__((address_space(3))) void*)&As[c * 8192 + (w * 32 + q * 8) * 64],
            16, 0, 0);
        const _Float16* gB = Bt + (size_t)(col0 + r) * K + kb + sslot * 8;
        __builtin_amdgcn_global_load_lds(
            (const __attribute__((address_space(1))) void*)gB,
            (__attribute__((address_space(3))) void*)&Bs[c * 8192 + (w * 32 + q * 8) * 64],
            16, 0, 0);
      }
    }
    __syncthreads();
#pragma unroll
    for (int c = 0; c < 2; ++c) {
#pragma unroll
      for (int kk = 0; kk < 2; ++kk) {
        half8 av[4], bv[4];
#pragma unroll
        for (int i = 0; i < 4; ++i) {
          int ra = fr_a + i * 16;
          int sa = (kk * 4 + fgrp) ^ (ra & 7);
          av[i] = *(const half8*)&As[c * 8192 + ra * 64 + sa * 8];
          int rb = fr_b + i * 16;
          int sb = (kk * 4 + fgrp) ^ (rb & 7);
          bv[i] = *(const half8*)&Bs[c * 8192 + rb * 64 + sb * 8];
        }
#pragma unroll
        for (int mi = 0; mi < 4; ++mi)
#pragma unroll
          for (int ni = 0; ni < 4; ++ni)
            acc[mi][ni] = __builtin_amdgcn_mfma_f32_16x16x32_f16(
                av[mi], bv[ni], acc[mi][ni], 0, 0, 0);
      }
    }
    if (ph + 1 < NCHUNK / 2) __syncthreads();
  }

  // D lane map: row=(l>>4)*4+reg, col=l&15
#pragma unroll
  for (int mi = 0; mi < 4; ++mi) {
#pragma unroll
    for (int r = 0; r < 4; ++r) {
      int grow = row0 + wm * 64 + mi * 16 + fgrp * 4 + r;
      if (grow >= M) continue;
      float rsv = (OUTMODE == 2) ? rs[grow] : 0.f;
#pragma unroll
      for (int ni = 0; ni < 4; ++ni) {
        int gcol = col0 + wn * 64 + ni * 16 + (l & 15);
        float v = acc[mi][ni][r];
        if (OUTMODE == 2) {
          v += rsv * cvec[gcol] + bias[gcol];
          v = fmaxf(v, 0.f);
        }
        outp[(size_t)grow * 256 + gcol] = (_Float16)v;
      }
    }
  }
}

// ---------------------------------------------------------------------------
// Aggregate (proven form): one wave per node, half4/lane, unroll x8/x4,
// 4 accumulators, w = dinv[col]*dinv[node]. NT col loads, NT h store.
// ---------------------------------------------------------------------------
template<bool DECODE>
__global__ __launch_bounds__(256) void aggregate_kernel(
    const _Float16* __restrict__ tmp, const int* __restrict__ row_ptr,
    const int* __restrict__ col, const float* __restrict__ dinv,
    const float* __restrict__ bias, _Float16* __restrict__ hout,
    const float* __restrict__ decW, const float* __restrict__ decb,
    float* __restrict__ out, int n) {
  int wave = threadIdx.x >> 6;
  int lane = threadIdx.x & 63;
  int node = blockIdx.x * 4 + wave;
  if (node >= n) return;
  const half4v* tmp4 = (const half4v*)tmp;
  float dn = dinv[node];
  float4 a0 = ((const float4*)bias)[lane];
  float4 a1 = make_float4(0.f, 0.f, 0.f, 0.f);
  float4 a2 = make_float4(0.f, 0.f, 0.f, 0.f);
  float4 a3 = make_float4(0.f, 0.f, 0.f, 0.f);
  int p = row_ptr[node], end = row_ptr[node + 1];

  for (; p + 8 <= end; p += 8) {
    int j0 = __builtin_nontemporal_load(&col[p + 0]);
    int j1 = __builtin_nontemporal_load(&col[p + 1]);
    int j2 = __builtin_nontemporal_load(&col[p + 2]);
    int j3 = __builtin_nontemporal_load(&col[p + 3]);
    int j4 = __builtin_nontemporal_load(&col[p + 4]);
    int j5 = __builtin_nontemporal_load(&col[p + 5]);
    int j6 = __builtin_nontemporal_load(&col[p + 6]);
    int j7 = __builtin_nontemporal_load(&col[p + 7]);
    float w0 = dinv[j0] * dn, w1 = dinv[j1] * dn, w2 = dinv[j2] * dn, w3 = dinv[j3] * dn;
    float w4 = dinv[j4] * dn, w5 = dinv[j5] * dn, w6 = dinv[j6] * dn, w7 = dinv[j7] * dn;
    half4v v0 = tmp4[(size_t)j0 * 64 + lane];
    half4v v1 = tmp4[(size_t)j1 * 64 + lane];
    half4v v2 = tmp4[(size_t)j2 * 64 + lane];
    half4v v3 = tmp4[(size_t)j3 * 64 + lane];
    half4v v4 = tmp4[(size_t)j4 * 64 + lane];
    half4v v5 = tmp4[(size_t)j5 * 64 + lane];
    half4v v6 = tmp4[(size_t)j6 * 64 + lane];
    half4v v7 = tmp4[(size_t)j7 * 64 + lane];
    fma4h(a0, w0, v0); fma4h(a1, w1, v1); fma4h(a2, w2, v2); fma4h(a3, w3, v3);
    fma4h(a0, w4, v4); fma4h(a1, w5, v5); fma4h(a2, w6, v6); fma4h(a3, w7, v7);
  }
  for (; p + 4 <= end; p += 4) {
    int j0 = __builtin_nontemporal_load(&col[p + 0]);
    int j1 = __builtin_nontemporal_load(&col[p + 1]);
    int j2 = __builtin_nontemporal_load(&col[p + 2]);
    int j3 = __builtin_nontemporal_load(&col[p + 3]);
    float w0 = dinv[j0] * dn, w1 = dinv[j1] * dn, w2 = dinv[j2] * dn, w3 = dinv[j3] * dn;
    half4v v0 = tmp4[(size_t)j0 * 64 + lane];
    half4v v1 = tmp4[(size_t)j1 * 64 + lane];
    half4v v2 = tmp4[(size_t)j2 * 64 + lane];
    half4v v3 = tmp4[(size_t)j3 * 64 + lane];
    fma4h(a0, w0, v0); fma4h(a1, w1, v1); fma4h(a2, w2, v2); fma4h(a3, w3, v3);
  }
  for (; p < end; ++p) {
    int j = __builtin_nontemporal_load(&col[p]);
    float s = dinv[j] * dn;
    half4v v = tmp4[(size_t)j * 64 + lane];
    fma4h(a0, s, v);
  }
  float4 acc;
  acc.x = fmaxf(a0.x + a1.x + a2.x + a3.x, 0.f);
  acc.y = fmaxf(a0.y + a1.y + a2.y + a3.y, 0.f);
  acc.z = fmaxf(a0.z + a1.z + a2.z + a3.z, 0.f);
  acc.w = fmaxf(a0.w + a1.w + a2.w + a3.w, 0.f);

  if (!DECODE) {
    half4v hv;
    hv.x = (_Float16)acc.x; hv.y = (_Float16)acc.y;
    hv.z = (_Float16)acc.z; hv.w = (_Float16)acc.w;
    __builtin_nontemporal_store(hv, &((half4v*)hout)[(size_t)node * 64 + lane]);
  } else {
    float4 w = ((const float4*)decW)[lane];
    float s = acc.x * w.x + acc.y * w.y + acc.z * w.z + acc.w * w.w;
#pragma unroll
    for (int off = 32; off > 0; off >>= 1) s += __shfl_xor(s, off);
    if (lane == 0) out[node] = s + decb[0];
  }
}

// ---------------------------------------------------------------------------

extern "C" void kernel_launch(void* const* d_in, const int* in_sizes, int n_in,
                              void* d_out, int out_size, void* d_ws, size_t ws_size,
                              hipStream_t stream) {
  const float* x      = (const float*)d_in[0];
  const int*   eidx   = (const int*)d_in[1];
  const float* enc_W  = (const float*)d_in[2];
  const float* enc_b  = (const float*)d_in[3];
  const float* W1     = (const float*)d_in[4];
  const float* b1     = (const float*)d_in[5];
  const float* W2     = (const float*)d_in[6];
  const float* b2     = (const float*)d_in[7];
  const float* W3     = (const float*)d_in[8];
  const float* b3     = (const float*)d_in[9];
  const float* dec_W  = (const float*)d_in[10];
  const float* dec_b  = (const float*)d_in[11];
  float* out = (float*)d_out;

  const int D_IN = 128;
  const int N = in_sizes[0] / D_IN;   // 50000
  const int E = in_sizes[1] / 2;      // 800000
  const int* src = eidx;
  const int* dst = eidx + E;

  // workspace layout (16B-aligned regions)
  _Float16* h    = (_Float16*)d_ws;                  // N*256 fp16
  _Float16* tmp  = h + (size_t)N * 256;              // N*256 fp16
  _Float16* xh   = tmp + (size_t)N * 256;            // N*128 fp16
  _Float16* a1   = xh + (size_t)N * 128;             // N*128 fp16
  _Float16* Wtf  = a1 + (size_t)N * 128;             // 256*128
  _Float16* Wt2  = Wtf + 256 * 128;                  // 256*256
  _Float16* Wt3  = Wt2 + 256 * 256;
  float* cvec    = (float*)(Wt3 + 256 * 256);        // 256
  float* rs      = cvec + 256;                       // N
  int*   deg     = (int*)(rs + N);                   // N
  float* dinv    = (float*)(deg + N);                // N
  int*   row_ptr = (int*)(dinv + N);                 // N+1
  int*   row_tmp = row_ptr + (N + 1);                // N
  int*   bsum    = row_tmp + N;                      // 64
  int*   boff    = bsum + 64;                        // 64
  int*   rank    = boff + 64;                        // E
  int*   col     = rank + E;                         // E+N

  dim3 blk(256);
  dim3 gEN((E + N + 255) / 256);
  int nb = (N + 1023) / 1024;                        // 49
  int nx4 = N * 32;                                  // x float4 count

  // ---- merged build: degree+rank, x cast, W2/W3 transpose, Wf fuse ----
  hipMemsetAsync(deg, 0, (size_t)N * 4, stream);
  int build_threads = E + nx4 + 2 * 256 * 256 + 129 * 256;
  build_kernel<<<(build_threads + 255) / 256, blk, 0, stream>>>(
      dst, deg, rank, E, x, xh, nx4, W2, W3, Wt2, Wt3,
      enc_W, enc_b, W1, Wtf, cvec);

  // ---- scan + atomic-free fill ----
  scan1_kernel<<<nb, 1024, 0, stream>>>(deg, dinv, row_tmp, bsum, N);
  scan2_kernel<<<1, 64, 0, stream>>>(bsum, boff, row_ptr, N, nb);
  scan3_kernel<<<nb, 1024, 0, stream>>>(row_tmp, boff, row_ptr, N);
  fill_csr_kernel<<<gEN, blk, 0, stream>>>(src, dst, row_ptr, rank, col, E, N);

  // ---- network ----
  dim3 gemm_grid(((N + 127) / 128) * 2);
  dim3 agg_grid((N + 3) / 4);
  dim3 aggx_grid((N + 7) / 8);

  // layer 1: a1 = A x (+rs); h = relu(a1 @ Wf + rs*cvec + b1)
  aggregate_x_kernel<<<aggx_grid, blk, 0, stream>>>(xh, row_ptr, col, dinv, a1, rs, N);
  mfma_gemm_kernel<2, 2><<<gemm_grid, blk, 0, stream>>>(a1, Wtf, b1, rs, cvec, h, N);
  // layer 2
  mfma_gemm_kernel<4, 0><<<gemm_grid, blk, 0, stream>>>(h, Wt2, nullptr, nullptr, nullptr, tmp, N);
  aggregate_kernel<false><<<agg_grid, blk, 0, stream>>>(tmp, row_ptr, col, dinv, b2, h,
                                                        nullptr, nullptr, nullptr, N);
  // layer 3 + fused decoder
  mfma_gemm_kernel<4, 0><<<gemm_grid, blk, 0, stream>>>(h, Wt3, nullptr, nullptr, nullptr, tmp, N);
  aggregate_kernel<true><<<agg_grid, blk, 0, stream>>>(tmp, row_ptr, col, dinv, b3, nullptr,
                                                       dec_W, dec_b, out, N);
}

// Round 15
// 290.052 us; speedup vs baseline: 1.0600x; 1.0600x over previous
//
#include <hip/hip_runtime.h>

// ---------------------------------------------------------------------------
// GCN forward, all-fp16 MFMA edition.
// Round 15: revert round-14 nontemporal hints (regressed: col is re-read by
//   4 kernels, NT bypass added refetch; NT stores hurt write-combining).
//   Keep the merged build kernel (launch-count saving). Aggregate bodies are
//   round-13's proven form. Aggregates at compulsory-byte floor
//   (~3.6-3.9 TB/s random-row-gather), CSR atomic/scatter-bound, GEMMs
//   latency-bound: structural floor expected ~290 us.
// ---------------------------------------------------------------------------

typedef __attribute__((ext_vector_type(8))) _Float16 half8;
typedef __attribute__((ext_vector_type(4))) _Float16 half4v;
typedef __attribute__((ext_vector_type(4))) float f32x4;

__device__ __forceinline__ void fma4h(float4& acc, float s, const half4v& v) {
  acc.x += s * (float)v.x;
  acc.y += s * (float)v.y;
  acc.z += s * (float)v.z;
  acc.w += s * (float)v.w;
}

// ---------------------------------------------------------------------------
// Merged build kernel: [0,E) degree count + rank; [E,E+nx4) x cast;
// then W2/W3 transpose-cast; then Wf = (encW@W1)^T fp16 + cvec = enc_b@W1.
// ---------------------------------------------------------------------------
__global__ void build_kernel(const int* __restrict__ dst, int* __restrict__ deg,
                             int* __restrict__ rank, int E,
                             const float* __restrict__ x, _Float16* __restrict__ xh, int nx4,
                             const float* __restrict__ W2, const float* __restrict__ W3,
                             _Float16* __restrict__ Wt2, _Float16* __restrict__ Wt3,
                             const float* __restrict__ encW, const float* __restrict__ enc_b,
                             const float* __restrict__ W1, _Float16* __restrict__ Wtf,
                             float* __restrict__ cvec) {
  int t = blockIdx.x * blockDim.x + threadIdx.x;
  if (t < E) {                              // degree + rank (single atomic pass)
    rank[t] = atomicAdd(&deg[dst[t]], 1);
    return;
  }
  int u = t - E;
  if (u < nx4) {                            // x f32 -> fp16 (float4-wide)
    float4 v = ((const float4*)x)[u];
    half4v h;
    h.x = (_Float16)v.x; h.y = (_Float16)v.y; h.z = (_Float16)v.z; h.w = (_Float16)v.w;
    ((half4v*)xh)[u] = h;
    return;
  }
  u -= nx4;
  if (u < 2 * 256 * 256) {                  // W2/W3 [256][256] -> Wt transposed
    int seg = u >> 16;
    int rem = u & 65535;
    int k = rem >> 8, n = rem & 255;
    const float* W = (seg == 0) ? W2 : W3;
    _Float16* Wt = (seg == 0) ? Wt2 : Wt3;
    Wt[(size_t)n * 256 + k] = (_Float16)W[rem];
    return;
  }
  u -= 2 * 256 * 256;
  if (u >= 129 * 256) return;               // fused weight: Wtf + cvec
  int k = u >> 8;                           // 0..127 = Wf rows; 128 = cvec
  int nn = u & 255;
  float s = 0.f;
  if (k < 128) {
    for (int m = 0; m < 256; ++m)
      s += encW[k * 256 + m] * W1[m * 256 + nn];
    Wtf[(size_t)nn * 128 + k] = (_Float16)s;
  } else {
    for (int m = 0; m < 256; ++m)
      s += enc_b[m] * W1[m * 256 + nn];
    cvec[nn] = s;
  }
}

// scan phase 1 + dinv fused (cnt[i] = deg[i]+1 folds the self-loop).
__global__ __launch_bounds__(1024) void scan1_kernel(const int* __restrict__ deg,
                                                     float* __restrict__ dinv,
                                                     int* __restrict__ row_tmp,
                                                     int* __restrict__ bsum, int n) {
  __shared__ int wsum[16];
  int tid = threadIdx.x, lane = tid & 63, wid = tid >> 6;
  int i = blockIdx.x * 1024 + tid;
  int d = (i < n) ? deg[i] + 1 : 0;
  if (i < n) dinv[i] = rsqrtf((float)d);
  int v = d;
  int s = v;
#pragma unroll
  for (int off = 1; off < 64; off <<= 1) {
    int t = __shfl_up(s, off, 64);
    if (lane >= off) s += t;
  }
  if (lane == 63) wsum[wid] = s;
  __syncthreads();
  int wadd = 0;
#pragma unroll
  for (int k = 0; k < 16; ++k) wadd += (k < wid) ? wsum[k] : 0;
  int incl = s + wadd;
  if (i < n) row_tmp[i] = incl - v;          // block-local exclusive
  if (tid == 1023) bsum[blockIdx.x] = incl;  // block total
}
__global__ __launch_bounds__(64) void scan2_kernel(const int* __restrict__ bsum,
                                                   int* __restrict__ boff,
                                                   int* __restrict__ row_ptr,
                                                   int n, int nb) {
  int lane = threadIdx.x;
  int v = (lane < nb) ? bsum[lane] : 0;
  int s = v;
#pragma unroll
  for (int off = 1; off < 64; off <<= 1) {
    int t = __shfl_up(s, off, 64);
    if (lane >= off) s += t;
  }
  if (lane < nb) boff[lane] = s - v;
  if (lane == nb - 1) row_ptr[n] = s;
}
__global__ __launch_bounds__(1024) void scan3_kernel(const int* __restrict__ row_tmp,
                                                     const int* __restrict__ boff,
                                                     int* __restrict__ row_ptr, int n) {
  int i = blockIdx.x * 1024 + threadIdx.x;
  if (i >= n) return;
  row_ptr[i] = row_tmp[i] + boff[blockIdx.x];
}

// fill edges + self-loops, NO atomics: pos = row_ptr[dst]+1+rank (slot 0 = self).
__global__ void fill_csr_kernel(const int* __restrict__ src, const int* __restrict__ dst,
                                const int* __restrict__ row_ptr, const int* __restrict__ rank,
                                int* __restrict__ col, int E, int n) {
  int t = blockIdx.x * blockDim.x + threadIdx.x;
  if (t < E) {
    int d = dst[t];
    col[row_ptr[d] + 1 + rank[t]] = src[t];
  } else if (t < E + n) {
    int i = t - E;
    col[row_ptr[i]] = i;
  }
}

// ---------------------------------------------------------------------------
// Aggregate x: a1 = A_hat @ xh ([N,128]), rs = A_hat row sums.
// 32-lane group per node, half4/lane, 8 nodes/block.
// ---------------------------------------------------------------------------
__global__ __launch_bounds__(256) void aggregate_x_kernel(
    const _Float16* __restrict__ xh, const int* __restrict__ row_ptr,
    const int* __restrict__ col, const float* __restrict__ dinv,
    _Float16* __restrict__ a1, float* __restrict__ rs, int n) {
  int grp = threadIdx.x >> 5;
  int gl = threadIdx.x & 31;
  int node = blockIdx.x * 8 + grp;
  if (node >= n) return;
  const half4v* x4 = (const half4v*)xh;
  float dn = dinv[node];
  float4 a0 = make_float4(0.f, 0.f, 0.f, 0.f);
  float4 b0 = make_float4(0.f, 0.f, 0.f, 0.f);
  float4 c0 = make_float4(0.f, 0.f, 0.f, 0.f);
  float4 e0 = make_float4(0.f, 0.f, 0.f, 0.f);
  float dsum = 0.f;
  int p = row_ptr[node], end = row_ptr[node + 1];

  for (; p + 8 <= end; p += 8) {
    int j0 = col[p + 0], j1 = col[p + 1], j2 = col[p + 2], j3 = col[p + 3];
    int j4 = col[p + 4], j5 = col[p + 5], j6 = col[p + 6], j7 = col[p + 7];
    float d0 = dinv[j0], d1 = dinv[j1], d2 = dinv[j2], d3 = dinv[j3];
    float d4 = dinv[j4], d5 = dinv[j5], d6 = dinv[j6], d7 = dinv[j7];
    half4v v0 = x4[(size_t)j0 * 32 + gl];
    half4v v1 = x4[(size_t)j1 * 32 + gl];
    half4v v2 = x4[(size_t)j2 * 32 + gl];
    half4v v3 = x4[(size_t)j3 * 32 + gl];
    half4v v4 = x4[(size_t)j4 * 32 + gl];
    half4v v5 = x4[(size_t)j5 * 32 + gl];
    half4v v6 = x4[(size_t)j6 * 32 + gl];
    half4v v7 = x4[(size_t)j7 * 32 + gl];
    fma4h(a0, d0, v0); fma4h(b0, d1, v1); fma4h(c0, d2, v2); fma4h(e0, d3, v3);
    fma4h(a0, d4, v4); fma4h(b0, d5, v5); fma4h(c0, d6, v6); fma4h(e0, d7, v7);
    dsum += ((d0 + d1) + (d2 + d3)) + ((d4 + d5) + (d6 + d7));
  }
  for (; p < end; ++p) {
    int j = col[p];
    float d = dinv[j];
    half4v v = x4[(size_t)j * 32 + gl];
    fma4h(a0, d, v);
    dsum += d;
  }
  float4 acc;
  acc.x = (a0.x + b0.x + c0.x + e0.x) * dn;
  acc.y = (a0.y + b0.y + c0.y + e0.y) * dn;
  acc.z = (a0.z + b0.z + c0.z + e0.z) * dn;
  acc.w = (a0.w + b0.w + c0.w + e0.w) * dn;
  half4v hv;
  hv.x = (_Float16)acc.x; hv.y = (_Float16)acc.y;
  hv.z = (_Float16)acc.z; hv.w = (_Float16)acc.w;
  ((half4v*)a1)[(size_t)node * 32 + gl] = hv;
  if (gl == 0) rs[node] = dsum * dn;
}

// ---------------------------------------------------------------------------
// fp16 MFMA GEMM (round-9 proven form). NCHUNK = K/64 (2 or 4).
// OUTMODE 0: f16 out. OUTMODE 2: +rs*cvec+bias, relu, f16 out.
// ---------------------------------------------------------------------------
template<int NCHUNK, int OUTMODE>
__global__ __launch_bounds__(256) void mfma_gemm_kernel(
    const _Float16* __restrict__ A, const _Float16* __restrict__ Bt,
    const float* __restrict__ bias, const float* __restrict__ rs,
    const float* __restrict__ cvec, _Float16* __restrict__ outp, int M) {
  constexpr int K = NCHUNK * 64;
  __shared__ __align__(16) _Float16 As[2 * 128 * 64];   // 32 KB
  __shared__ __align__(16) _Float16 Bs[2 * 128 * 64];   // 32 KB
  int row0 = (blockIdx.x >> 1) * 128;
  int col0 = (blockIdx.x & 1) * 128;
  int tid = threadIdx.x;
  int w = tid >> 6, l = tid & 63;
  int wm = w >> 1, wn = w & 1;

  f32x4 acc[4][4] = {};

  int srow = l >> 3;
  int sslot = (l & 7) ^ srow;
  int fr_a = wm * 64 + (l & 15);
  int fr_b = wn * 64 + (l & 15);
  int fgrp = l >> 4;

#pragma unroll
  for (int ph = 0; ph < NCHUNK / 2; ++ph) {
#pragma unroll
    for (int c = 0; c < 2; ++c) {
      int kb = (ph * 2 + c) * 64;
#pragma unroll
      for (int q = 0; q < 4; ++q) {
        int r = w * 32 + q * 8 + srow;
        int ga_row = row0 + r; if (ga_row >= M) ga_row = M - 1;
        const _Float16* gA = A + (size_t)ga_row * K + kb + sslot * 8;
        __builtin_amdgcn_global_load_lds(
            (const __attribute__((address_space(1))) void*)gA,
            (__attribute__((address_space(3))) void*)&As[c * 8192 + (w * 32 + q * 8) * 64],
            16, 0, 0);
        const _Float16* gB = Bt + (size_t)(col0 + r) * K + kb + sslot * 8;
        __builtin_amdgcn_global_load_lds(
            (const __attribute__((address_space(1))) void*)gB,
            (__attribute__((address_space(3))) void*)&Bs[c * 8192 + (w * 32 + q * 8) * 64],
            16, 0, 0);
      }
    }
    __syncthreads();
#pragma unroll
    for (int c = 0; c < 2; ++c) {
#pragma unroll
      for (int kk = 0; kk < 2; ++kk) {
        half8 av[4], bv[4];
#pragma unroll
        for (int i = 0; i < 4; ++i) {
          int ra = fr_a + i * 16;
          int sa = (kk * 4 + fgrp) ^ (ra & 7);
          av[i] = *(const half8*)&As[c * 8192 + ra * 64 + sa * 8];
          int rb = fr_b + i * 16;
          int sb = (kk * 4 + fgrp) ^ (rb & 7);
          bv[i] = *(const half8*)&Bs[c * 8192 + rb * 64 + sb * 8];
        }
#pragma unroll
        for (int mi = 0; mi < 4; ++mi)
#pragma unroll
          for (int ni = 0; ni < 4; ++ni)
            acc[mi][ni] = __builtin_amdgcn_mfma_f32_16x16x32_f16(
                av[mi], bv[ni], acc[mi][ni], 0, 0, 0);
      }
    }
    if (ph + 1 < NCHUNK / 2) __syncthreads();
  }

  // D lane map: row=(l>>4)*4+reg, col=l&15
#pragma unroll
  for (int mi = 0; mi < 4; ++mi) {
#pragma unroll
    for (int r = 0; r < 4; ++r) {
      int grow = row0 + wm * 64 + mi * 16 + fgrp * 4 + r;
      if (grow >= M) continue;
      float rsv = (OUTMODE == 2) ? rs[grow] : 0.f;
#pragma unroll
      for (int ni = 0; ni < 4; ++ni) {
        int gcol = col0 + wn * 64 + ni * 16 + (l & 15);
        float v = acc[mi][ni][r];
        if (OUTMODE == 2) {
          v += rsv * cvec[gcol] + bias[gcol];
          v = fmaxf(v, 0.f);
        }
        outp[(size_t)grow * 256 + gcol] = (_Float16)v;
      }
    }
  }
}

// ---------------------------------------------------------------------------
// Aggregate (round-13 proven form, NT hints reverted): one wave per node,
// half4/lane, unroll x8/x4, 4 accumulators, w = dinv[col]*dinv[node].
// ---------------------------------------------------------------------------
template<bool DECODE>
__global__ __launch_bounds__(256) void aggregate_kernel(
    const _Float16* __restrict__ tmp, const int* __restrict__ row_ptr,
    const int* __restrict__ col, const float* __restrict__ dinv,
    const float* __restrict__ bias, _Float16* __restrict__ hout,
    const float* __restrict__ decW, const float* __restrict__ decb,
    float* __restrict__ out, int n) {
  int wave = threadIdx.x >> 6;
  int lane = threadIdx.x & 63;
  int node = blockIdx.x * 4 + wave;
  if (node >= n) return;
  const half4v* tmp4 = (const half4v*)tmp;
  float dn = dinv[node];
  float4 a0 = ((const float4*)bias)[lane];
  float4 a1 = make_float4(0.f, 0.f, 0.f, 0.f);
  float4 a2 = make_float4(0.f, 0.f, 0.f, 0.f);
  float4 a3 = make_float4(0.f, 0.f, 0.f, 0.f);
  int p = row_ptr[node], end = row_ptr[node + 1];

  for (; p + 8 <= end; p += 8) {
    int j0 = col[p + 0], j1 = col[p + 1], j2 = col[p + 2], j3 = col[p + 3];
    int j4 = col[p + 4], j5 = col[p + 5], j6 = col[p + 6], j7 = col[p + 7];
    float w0 = dinv[j0] * dn, w1 = dinv[j1] * dn, w2 = dinv[j2] * dn, w3 = dinv[j3] * dn;
    float w4 = dinv[j4] * dn, w5 = dinv[j5] * dn, w6 = dinv[j6] * dn, w7 = dinv[j7] * dn;
    half4v v0 = tmp4[(size_t)j0 * 64 + lane];
    half4v v1 = tmp4[(size_t)j1 * 64 + lane];
    half4v v2 = tmp4[(size_t)j2 * 64 + lane];
    half4v v3 = tmp4[(size_t)j3 * 64 + lane];
    half4v v4 = tmp4[(size_t)j4 * 64 + lane];
    half4v v5 = tmp4[(size_t)j5 * 64 + lane];
    half4v v6 = tmp4[(size_t)j6 * 64 + lane];
    half4v v7 = tmp4[(size_t)j7 * 64 + lane];
    fma4h(a0, w0, v0); fma4h(a1, w1, v1); fma4h(a2, w2, v2); fma4h(a3, w3, v3);
    fma4h(a0, w4, v4); fma4h(a1, w5, v5); fma4h(a2, w6, v6); fma4h(a3, w7, v7);
  }
  for (; p + 4 <= end; p += 4) {
    int j0 = col[p + 0], j1 = col[p + 1], j2 = col[p + 2], j3 = col[p + 3];
    float w0 = dinv[j0] * dn, w1 = dinv[j1] * dn, w2 = dinv[j2] * dn, w3 = dinv[j3] * dn;
    half4v v0 = tmp4[(size_t)j0 * 64 + lane];
    half4v v1 = tmp4[(size_t)j1 * 64 + lane];
    half4v v2 = tmp4[(size_t)j2 * 64 + lane];
    half4v v3 = tmp4[(size_t)j3 * 64 + lane];
    fma4h(a0, w0, v0); fma4h(a1, w1, v1); fma4h(a2, w2, v2); fma4h(a3, w3, v3);
  }
  for (; p < end; ++p) {
    int j = col[p];
    float s = dinv[j] * dn;
    half4v v = tmp4[(size_t)j * 64 + lane];
    fma4h(a0, s, v);
  }
  float4 acc;
  acc.x = fmaxf(a0.x + a1.x + a2.x + a3.x, 0.f);
  acc.y = fmaxf(a0.y + a1.y + a2.y + a3.y, 0.f);
  acc.z = fmaxf(a0.z + a1.z + a2.z + a3.z, 0.f);
  acc.w = fmaxf(a0.w + a1.w + a2.w + a3.w, 0.f);

  if (!DECODE) {
    half4v hv;
    hv.x = (_Float16)acc.x; hv.y = (_Float16)acc.y;
    hv.z = (_Float16)acc.z; hv.w = (_Float16)acc.w;
    ((half4v*)hout)[(size_t)node * 64 + lane] = hv;
  } else {
    float4 w = ((const float4*)decW)[lane];
    float s = acc.x * w.x + acc.y * w.y + acc.z * w.z + acc.w * w.w;
#pragma unroll
    for (int off = 32; off > 0; off >>= 1) s += __shfl_xor(s, off);
    if (lane == 0) out[node] = s + decb[0];
  }
}

// ---------------------------------------------------------------------------

extern "C" void kernel_launch(void* const* d_in, const int* in_sizes, int n_in,
                              void* d_out, int out_size, void* d_ws, size_t ws_size,
                              hipStream_t stream) {
  const float* x      = (const float*)d_in[0];
  const int*   eidx   = (const int*)d_in[1];
  const float* enc_W  = (const float*)d_in[2];
  const float* enc_b  = (const float*)d_in[3];
  const float* W1     = (const float*)d_in[4];
  const float* b1     = (const float*)d_in[5];
  const float* W2     = (const float*)d_in[6];
  const float* b2     = (const float*)d_in[7];
  const float* W3     = (const float*)d_in[8];
  const float* b3     = (const float*)d_in[9];
  const float* dec_W  = (const float*)d_in[10];
  const float* dec_b  = (const float*)d_in[11];
  float* out = (float*)d_out;

  const int D_IN = 128;
  const int N = in_sizes[0] / D_IN;   // 50000
  const int E = in_sizes[1] / 2;      // 800000
  const int* src = eidx;
  const int* dst = eidx + E;

  // workspace layout (16B-aligned regions)
  _Float16* h    = (_Float16*)d_ws;                  // N*256 fp16
  _Float16* tmp  = h + (size_t)N * 256;              // N*256 fp16
  _Float16* xh   = tmp + (size_t)N * 256;            // N*128 fp16
  _Float16* a1   = xh + (size_t)N * 128;             // N*128 fp16
  _Float16* Wtf  = a1 + (size_t)N * 128;             // 256*128
  _Float16* Wt2  = Wtf + 256 * 128;                  // 256*256
  _Float16* Wt3  = Wt2 + 256 * 256;
  float* cvec    = (float*)(Wt3 + 256 * 256);        // 256
  float* rs      = cvec + 256;                       // N
  int*   deg     = (int*)(rs + N);                   // N
  float* dinv    = (float*)(deg + N);                // N
  int*   row_ptr = (int*)(dinv + N);                 // N+1
  int*   row_tmp = row_ptr + (N + 1);                // N
  int*   bsum    = row_tmp + N;                      // 64
  int*   boff    = bsum + 64;                        // 64
  int*   rank    = boff + 64;                        // E
  int*   col     = rank + E;                         // E+N

  dim3 blk(256);
  dim3 gEN((E + N + 255) / 256);
  int nb = (N + 1023) / 1024;                        // 49
  int nx4 = N * 32;                                  // x float4 count

  // ---- merged build: degree+rank, x cast, W2/W3 transpose, Wf fuse ----
  hipMemsetAsync(deg, 0, (size_t)N * 4, stream);
  int build_threads = E + nx4 + 2 * 256 * 256 + 129 * 256;
  build_kernel<<<(build_threads + 255) / 256, blk, 0, stream>>>(
      dst, deg, rank, E, x, xh, nx4, W2, W3, Wt2, Wt3,
      enc_W, enc_b, W1, Wtf, cvec);

  // ---- scan + atomic-free fill ----
  scan1_kernel<<<nb, 1024, 0, stream>>>(deg, dinv, row_tmp, bsum, N);
  scan2_kernel<<<1, 64, 0, stream>>>(bsum, boff, row_ptr, N, nb);
  scan3_kernel<<<nb, 1024, 0, stream>>>(row_tmp, boff, row_ptr, N);
  fill_csr_kernel<<<gEN, blk, 0, stream>>>(src, dst, row_ptr, rank, col, E, N);

  // ---- network ----
  dim3 gemm_grid(((N + 127) / 128) * 2);
  dim3 agg_grid((N + 3) / 4);
  dim3 aggx_grid((N + 7) / 8);

  // layer 1: a1 = A x (+rs); h = relu(a1 @ Wf + rs*cvec + b1)
  aggregate_x_kernel<<<aggx_grid, blk, 0, stream>>>(xh, row_ptr, col, dinv, a1, rs, N);
  mfma_gemm_kernel<2, 2><<<gemm_grid, blk, 0, stream>>>(a1, Wtf, b1, rs, cvec, h, N);
  // layer 2
  mfma_gemm_kernel<4, 0><<<gemm_grid, blk, 0, stream>>>(h, Wt2, nullptr, nullptr, nullptr, tmp, N);
  aggregate_kernel<false><<<agg_grid, blk, 0, stream>>>(tmp, row_ptr, col, dinv, b2, h,
                                                        nullptr, nullptr, nullptr, N);
  // layer 3 + fused decoder
  mfma_gemm_kernel<4, 0><<<gemm_grid, blk, 0, stream>>>(h, Wt3, nullptr, nullptr, nullptr, tmp, N);
  aggregate_kernel<true><<<agg_grid, blk, 0, stream>>>(tmp, row_ptr, col, dinv, b3, nullptr,
                                                       dec_W, dec_b, out, N);
}